// Round 1
// baseline (983.652 us; speedup 1.0000x reference)
//
#include <hip/hip_runtime.h>
#include <stdint.h>

// Round 8: replace the 3-kernel sort pipeline with a single-pass u64 atomic
// histogram.
//  Round 7 post-mortem: top-5 dispatches are ALL harness workspace-poison
//  fills (1 GiB @ ~160us, fixed). Our kernels sum to ~345us against a 65us
//  traffic roofline; k_accum's per-row segment reads (~27 B each, 300 blocks)
//  and k_bin's double LDS-atomic pass are the overhead.
//  Fix: the output histogram is only 614,400 cells x 8 B = 4.9 MB (L3-
//  resident). Uniform-random events => ~27 events/cell, no contention.
//  One fire-and-forget u64 atomicAdd per event: (1<<40) | q21(wt).
//  Traffic: 268 MB input + 16.7M L3 RMWs (overlapped) + 10 MB convert.
//
// cell = (dt*2+p)*76800 + tok*300 + pos   (8 x 256 x 300 = 614,400)
// ws bytes: table u64[NCELL] = 4,915,200.

#define TPB 256
#define EVT 8                       // events per thread; 8192 blocks at n=2^24
#define NCELL 614400                // 8 * 256 * 300
#define OUT_CH_STRIDE 76800         // 256*300
#define OUT_DP_STRIDE 153600        // 2*256*300

__device__ __forceinline__ void classify_cell(const float4 e, const float t0,
                                              const float d_wt, const float d_dt,
                                              int& cell, float& wt) {
    const float c1 = (float)(319.0 / 20.0 + 1e-4);   // W/PW + B
    const float c2 = (float)(239.0 / 15.0 + 1e-4);   // H/PH + B
    const int pos = (int)(floorf(e.y / c1) + floorf(e.z / c2) * 20.0f);
    const int tok = (int)(floorf(fmodf(e.y, c1)) + floorf(fmodf(e.z, c2)) * 16.0f);
    const int dt = (int)floorf(4.0f * (e.x - t0) / d_dt);
    const int p  = (int)e.w;
    cell = (dt * 2 + p) * OUT_CH_STRIDE + tok * 300 + pos;
    wt = (e.x - t0) / d_wt;
}

__global__ __launch_bounds__(TPB) void k_hist(const float4* __restrict__ x,
                                              unsigned long long* __restrict__ table,
                                              int n) {
    const float* xf = (const float*)x;
    const float t0 = xf[0];
    const float tlast = xf[(size_t)(n - 1) * 4];
    const float d_wt = tlast - t0 + 1e-4f;
    const float d_dt = tlast - t0 + 1.0f;

    const int beg = blockIdx.x * (TPB * EVT);
    if (beg + TPB * EVT <= n) {
        #pragma unroll
        for (int k = 0; k < EVT; ++k) {
            const float4 e = x[beg + threadIdx.x + k * TPB];
            int cell; float wt;
            classify_cell(e, t0, d_wt, d_dt, cell, wt);
            uint32_t q = (uint32_t)(wt * 2097152.0f);          // q21
            q = q > 2097151u ? 2097151u : q;
            // fire-and-forget (return value unused -> no vmcnt stall)
            atomicAdd(&table[cell], (1ULL << 40) | (unsigned long long)q);
        }
    } else {
        #pragma unroll
        for (int k = 0; k < EVT; ++k) {
            const int i = beg + threadIdx.x + k * TPB;
            if (i < n) {
                const float4 e = x[i];
                int cell; float wt;
                classify_cell(e, t0, d_wt, d_dt, cell, wt);
                uint32_t q = (uint32_t)(wt * 2097152.0f);
                q = q > 2097151u ? 2097151u : q;
                atomicAdd(&table[cell], (1ULL << 40) | (unsigned long long)q);
            }
        }
    }
}

// 614,400 cells -> 1,228,800 floats, each written exactly once (no out memset).
__global__ __launch_bounds__(256) void k_out(const unsigned long long* __restrict__ table,
                                             float* __restrict__ out) {
    const int i = blockIdx.x * 256 + threadIdx.x;   // cell id, grid covers NCELL
    const unsigned long long v = table[i];
    const int pos = i % 300;
    const int tmp = i / 300;
    const int tok = tmp & 255;
    const int dp  = tmp >> 8;
    const float cntf = (float)(uint32_t)(v >> 40);
    const float wts  = (float)(v & ((1ULL << 40) - 1)) * (1.0f / 2097152.0f);
    const int base0 = dp * OUT_DP_STRIDE + tok * 300 + pos;
    out[base0] = cntf;                     // channel 0: count
    out[base0 + OUT_CH_STRIDE] = wts;      // channel 1: wt sum
}

// ---- fallback (ws too small) ----
__device__ __forceinline__ void classify_full(const float4 e, const float t0,
                                              const float d_wt, const float d_dt,
                                              int& bucket, int& tok, float& wt) {
    const float c1 = (float)(319.0 / 20.0 + 1e-4);
    const float c2 = (float)(239.0 / 15.0 + 1e-4);
    const int pos = (int)(floorf(e.y / c1) + floorf(e.z / c2) * 20.0f);
    tok = (int)(floorf(fmodf(e.y, c1)) + floorf(fmodf(e.z, c2)) * 16.0f);
    const int dt = (int)floorf(4.0f * (e.x - t0) / d_dt);
    const int p  = (int)e.w;
    bucket = (dt * 2 + p) * 300 + pos;
    wt = (e.x - t0) / d_wt;
}

__global__ __launch_bounds__(TPB) void e2src_hist_atomic(const float4* __restrict__ x,
                                                         float* __restrict__ out, int n) {
    const float* xf = (const float*)x;
    const float t0 = xf[0];
    const float tlast = xf[(size_t)(n - 1) * 4];
    const float d_wt = tlast - t0 + 1e-4f;
    const float d_dt = tlast - t0 + 1.0f;
    int i = blockIdx.x * blockDim.x + threadIdx.x;
    const int stride = gridDim.x * blockDim.x;
    for (; i < n; i += stride) {
        float4 e = x[i];
        int bucket, tok; float wt;
        classify_full(e, t0, d_wt, d_dt, bucket, tok, wt);
        const int dp = bucket / 300, pos = bucket % 300;
        const int base = dp * OUT_DP_STRIDE + tok * 300 + pos;
        unsafeAtomicAdd(out + base, 1.0f);
        unsafeAtomicAdd(out + base + OUT_CH_STRIDE, wt);
    }
}

extern "C" void kernel_launch(void* const* d_in, const int* in_sizes, int n_in,
                              void* d_out, int out_size, void* d_ws, size_t ws_size,
                              hipStream_t stream) {
    const float* x = (const float*)d_in[0];
    float* out = (float*)d_out;
    const int n = in_sizes[0] / 4;

    const size_t need = (size_t)NCELL * 8u;   // 4,915,200 bytes

    if (ws_size < need || n <= 0) {
        hipMemsetAsync(d_out, 0, (size_t)out_size * sizeof(float), stream);
        if (n > 0)
            hipLaunchKernelGGL(e2src_hist_atomic, dim3(8192), dim3(TPB), 0, stream,
                               (const float4*)x, out, n);
        return;
    }

    unsigned long long* table = (unsigned long long*)d_ws;
    hipMemsetAsync(d_ws, 0, need, stream);

    const int blocks = (n + TPB * EVT - 1) / (TPB * EVT);
    hipLaunchKernelGGL(k_hist, dim3(blocks), dim3(TPB), 0, stream,
                       (const float4*)x, table, n);
    hipLaunchKernelGGL(k_out, dim3(NCELL / 256), dim3(256), 0, stream,
                       table, out);
    // k_out writes every output exactly once -> no out memset needed.
}

// Round 2
// 442.360 us; speedup vs baseline: 2.2236x; 2.2236x over previous
//
#include <hip/hip_runtime.h>
#include <stdint.h>

// Round 9: revert round-8's global-atomic histogram (device u64 atomics are
// memory-side on MI355X: WRITE_SIZE showed 16.7M x 32 B = 537 MB, ~23 G
// atomics/s, 728 us). Back to the sort pipeline, restructured where the
// round-7 model said the time actually goes:
//  k_accum: GACC 8->16 (NG=150), 16 row-slices -> 2400 blocks, 32 KB LDS
//           hist -> 4 blocks/CU (32 waves/CU, was 8). Payload spans read by
//           16-lane quarters (coalesced) instead of serial per-thread loops.
//           Partials to ws; k_out sums 16 partials with coalesced R+W
//           (key = tok*16+c so consecutive cells -> consecutive pos).
//  k_bin:   single LDS-atomic pass (phase-1 atomicAdd returns rank, stashed
//           in bk bits 12..22); phase-3 is a plain store.
//
// payload word: tok<<24 | (bucket&15)<<20 | q20(wt).  hist key = w>>20.
// ws: payload u32*n | pfx u16[B1][NG] | pfxT u16[NG][B1] | partial u64[S][NG][4096]

#define TPB 256
#define B1 8192
#define CHUNK 2048                 // B1*CHUNK = 2^24 = n
#define EVT (CHUNK / TPB)          // 8 events per thread
#define NBUCKET 2400
#define SCAN_PER 10                // ceil(NBUCKET/TPB)
#define GACC 16                    // buckets per group
#define NG (NBUCKET / GACC)        // 150 groups
#define SLICES 16
#define RPS (B1 / SLICES)          // 512 rows per slice
#define HCELLS (GACC * 256)        // 4096 cells per group
#define ATPB 512                   // k_accum block size (8 waves)
#define OUT_CH_STRIDE 76800        // 256*300
#define OUT_DP_STRIDE 153600       // 2*256*300

__device__ __forceinline__ void classify_full(const float4 e, const float t0,
                                              const float d_wt, const float d_dt,
                                              int& bucket, int& tok, float& wt) {
    const float c1 = (float)(319.0 / 20.0 + 1e-4);   // W/PW + B
    const float c2 = (float)(239.0 / 15.0 + 1e-4);   // H/PH + B
    const int pos = (int)(floorf(e.y / c1) + floorf(e.z / c2) * 20.0f);
    tok = (int)(floorf(fmodf(e.y, c1)) + floorf(fmodf(e.z, c2)) * 16.0f);
    const int dt = (int)floorf(4.0f * (e.x - t0) / d_dt);
    const int p  = (int)e.w;
    bucket = (dt * 2 + p) * 300 + pos;
    wt = (e.x - t0) / d_wt;
}

__global__ __launch_bounds__(TPB) void k_bin(const float4* __restrict__ x,
                                             uint32_t* __restrict__ payload,
                                             uint16_t* __restrict__ pfx,
                                             int n) {
    __shared__ uint32_t stage[CHUNK];     // 8 KB
    __shared__ uint32_t cnt[NBUCKET];     // 9.6 KB: counts, then prefixes
    __shared__ uint32_t wsum[TPB / 64];

    for (int i = threadIdx.x; i < NBUCKET; i += TPB) cnt[i] = 0;
    __syncthreads();

    const float* xf = (const float*)x;
    const float t0 = xf[0];
    const float tlast = xf[(size_t)(n - 1) * 4];
    const float d_wt = tlast - t0 + 1e-4f;
    const float d_dt = tlast - t0 + 1.0f;

    const int beg = blockIdx.x * CHUNK;
    const bool full = (beg + CHUNK <= n);

    // phase 1: classify once; atomicAdd returns within-bucket rank (stash it)
    uint32_t pk[EVT];
    uint32_t bk[EVT];
    if (full) {
        #pragma unroll
        for (int k = 0; k < EVT; ++k) {
            float4 e = x[beg + threadIdx.x + k * TPB];
            int bucket, tok; float wt;
            classify_full(e, t0, d_wt, d_dt, bucket, tok, wt);
            uint32_t q = (uint32_t)(wt * 1048576.0f);          // q20
            q = q > 1048575u ? 1048575u : q;
            pk[k] = ((uint32_t)tok << 24) | ((uint32_t)(bucket & 15) << 20) | q;
            uint32_t rank = atomicAdd(&cnt[bucket], 1u);
            bk[k] = (uint32_t)bucket | (rank << 12);           // bucket:12 rank:11
        }
    } else {
        #pragma unroll
        for (int k = 0; k < EVT; ++k) {
            const int i = beg + threadIdx.x + k * TPB;
            if (i < n) {
                float4 e = x[i];
                int bucket, tok; float wt;
                classify_full(e, t0, d_wt, d_dt, bucket, tok, wt);
                uint32_t q = (uint32_t)(wt * 1048576.0f);
                q = q > 1048575u ? 1048575u : q;
                pk[k] = ((uint32_t)tok << 24) | ((uint32_t)(bucket & 15) << 20) | q;
                uint32_t rank = atomicAdd(&cnt[bucket], 1u);
                bk[k] = (uint32_t)bucket | (rank << 12);
            } else {
                bk[k] = 0xFFFFFFFFu;
            }
        }
    }
    __syncthreads();

    // phase 2: block-local exclusive scan of NBUCKET counts
    uint32_t v[SCAN_PER];
    uint32_t sum = 0;
    const int base_i = threadIdx.x * SCAN_PER;
    #pragma unroll
    for (int j = 0; j < SCAN_PER; ++j) {
        int idx = base_i + j;
        uint32_t c = (idx < NBUCKET) ? cnt[idx] : 0u;
        v[j] = sum;
        sum += c;
    }
    uint32_t inc = sum;
    #pragma unroll
    for (int off = 1; off < 64; off <<= 1) {
        uint32_t u = __shfl_up(inc, off, 64);
        if ((threadIdx.x & 63) >= off) inc += u;
    }
    const int wid = threadIdx.x >> 6, lid = threadIdx.x & 63;
    if (lid == 63) wsum[wid] = inc;
    __syncthreads();
    uint32_t woff = 0;
    for (int w = 0; w < wid; ++w) woff += wsum[w];
    const uint32_t excl = woff + inc - sum;

    uint16_t* prow = pfx + (size_t)blockIdx.x * NG;
    #pragma unroll
    for (int j = 0; j < SCAN_PER; ++j) {
        int idx = base_i + j;
        if (idx < NBUCKET) {
            uint32_t p = excl + v[j];
            cnt[idx] = p;                        // exclusive prefix (read-only below)
            if ((idx & 15) == 0) prow[idx >> 4] = (uint16_t)p;   // group start
        }
    }
    __syncthreads();

    // phase 3: plain indexed store (no second atomic pass)
    if (full) {
        #pragma unroll
        for (int k = 0; k < EVT; ++k)
            stage[cnt[bk[k] & 0xFFFu] + (bk[k] >> 12)] = pk[k];
    } else {
        #pragma unroll
        for (int k = 0; k < EVT; ++k)
            if (bk[k] != 0xFFFFFFFFu)
                stage[cnt[bk[k] & 0xFFFu] + (bk[k] >> 12)] = pk[k];
    }
    __syncthreads();

    // phase 4: coalesced LDS -> global writeout
    const int end = min(beg + CHUNK, n);
    const int cntE = end > beg ? end - beg : 0;
    uint32_t* pbase = payload + (size_t)blockIdx.x * CHUNK;
    const int n4 = cntE >> 2;
    const uint4* s4 = (const uint4*)stage;
    uint4* g4 = (uint4*)pbase;
    for (int i = threadIdx.x; i < n4; i += TPB) g4[i] = s4[i];
    for (int i = (n4 << 2) + threadIdx.x; i < cntE; i += TPB) pbase[i] = stage[i];
}

// pfx [B1][NG] u16 -> pfxT [NG][B1] u16 (coalesced offset reads in k_accum)
__global__ __launch_bounds__(256) void k_transpose(const uint16_t* __restrict__ in,
                                                   uint16_t* __restrict__ out) {
    __shared__ uint16_t tile[32][33];
    const int c0 = blockIdx.x * 32;    // NG cols: 5 tiles (guarded, 150 not /32)
    const int r0 = blockIdx.y * 32;    // B1 rows: 256 tiles
    const int tx = threadIdx.x & 31;
    const int ty = threadIdx.x >> 5;   // 0..7
    for (int j = ty; j < 32; j += 8)
        if (c0 + tx < NG)
            tile[j][tx] = in[(size_t)(r0 + j) * NG + (c0 + tx)];
    __syncthreads();
    for (int j = ty; j < 32; j += 8)
        if (c0 + j < NG)
            out[(size_t)(c0 + j) * B1 + (r0 + tx)] = tile[tx][j];
}

// One block per (group, row-slice): 150 x 16 = 2400 blocks, 32 KB LDS hist
// -> 4 blocks/CU, 32 waves/CU. Each wave owns 64 rows; 16-lane quarters
// stream each row's payload span (coalesced u32 runs).
__global__ __launch_bounds__(ATPB) void k_accum(const uint32_t* __restrict__ payload,
                                                const uint16_t* __restrict__ pfxT,
                                                unsigned long long* __restrict__ partial,
                                                int n) {
    const int g = blockIdx.x % NG;
    const int s = blockIdx.x / NG;

    __shared__ unsigned long long hist[HCELLS];   // 32 KB: (tok*16+c) -> cnt<<40 | q20sum
    for (int i = threadIdx.x; i < HCELLS; i += ATPB) hist[i] = 0ULL;
    __syncthreads();

    const uint16_t* colb = pfxT + (size_t)g * B1;
    const bool last = (g == NG - 1);
    const uint16_t* cole = colb + B1;             // valid iff !last

    const int wid = threadIdx.x >> 6, lid = threadIdx.x & 63;
    const int r0 = s * RPS + wid * 64;            // 8 waves x 64 rows = 512 = RPS

    const int row = r0 + lid;
    uint32_t vb = colb[row];                      // coalesced u16 loads
    uint32_t ve;
    if (!last) {
        ve = cole[row];
    } else {
        int rc = n - row * CHUNK;
        ve = rc < 0 ? 0 : (rc > CHUNK ? CHUNK : rc);
    }

    const int q4 = lid >> 4;                      // quarter 0..3
    const int ql = lid & 15;
    for (int r = 0; r < 64; r += 4) {
        const int rr = r + q4;
        const uint32_t sb = __shfl(vb, rr, 64);
        const uint32_t se = __shfl(ve, rr, 64);
        const uint32_t* seg = payload + (size_t)(r0 + rr) * CHUNK;
        for (uint32_t j = sb + ql; j < se; j += 16) {
            const uint32_t w = seg[j];
            atomicAdd(&hist[w >> 20],
                      (1ULL << 40) | (unsigned long long)(w & 0xFFFFFu));
        }
    }
    __syncthreads();

    // coalesced partial writeout (every cell written -> no ws pre-zero)
    unsigned long long* pp = partial + ((size_t)s * NG + g) * HCELLS;
    for (int i = threadIdx.x; i < HCELLS; i += ATPB) pp[i] = hist[i];
}

// Sum 16 partials per cell; coalesced reads AND writes (consecutive cells ->
// consecutive pos because key = tok*16 + c). 614,400 cells, each out written
// exactly once -> no out memset.
__global__ __launch_bounds__(256) void k_out(const unsigned long long* __restrict__ partial,
                                             float* __restrict__ out) {
    const int i = blockIdx.x * 256 + threadIdx.x;   // cell id
    unsigned long long v = 0ULL;
    #pragma unroll
    for (int s = 0; s < SLICES; ++s)
        v += partial[(size_t)s * (NG * HCELLS) + i];
    const int g = i >> 12;
    const int idx = i & 4095;
    const int tok = idx >> 4;
    const int c = idx & 15;
    const int b = g * GACC + c;
    const int pos = b % 300;
    const int dp = b / 300;
    const float cntf = (float)(uint32_t)(v >> 40);
    const float wts  = (float)(v & ((1ULL << 40) - 1)) * (1.0f / 1048576.0f);
    const int base0 = dp * OUT_DP_STRIDE + tok * 300 + pos;
    out[base0] = cntf;                     // channel 0: count
    out[base0 + OUT_CH_STRIDE] = wts;      // channel 1: wt sum
}

// ---- fallback (ws too small / n out of range) ----
__global__ __launch_bounds__(TPB) void e2src_hist_atomic(const float4* __restrict__ x,
                                                         float* __restrict__ out, int n) {
    const float* xf = (const float*)x;
    const float t0 = xf[0];
    const float tlast = xf[(size_t)(n - 1) * 4];
    const float d_wt = tlast - t0 + 1e-4f;
    const float d_dt = tlast - t0 + 1.0f;
    int i = blockIdx.x * blockDim.x + threadIdx.x;
    const int stride = gridDim.x * blockDim.x;
    for (; i < n; i += stride) {
        float4 e = x[i];
        int bucket, tok; float wt;
        classify_full(e, t0, d_wt, d_dt, bucket, tok, wt);
        const int dp = bucket / 300, pos = bucket % 300;
        const int base = dp * OUT_DP_STRIDE + tok * 300 + pos;
        unsafeAtomicAdd(out + base, 1.0f);
        unsafeAtomicAdd(out + base + OUT_CH_STRIDE, wt);
    }
}

extern "C" void kernel_launch(void* const* d_in, const int* in_sizes, int n_in,
                              void* d_out, int out_size, void* d_ws, size_t ws_size,
                              hipStream_t stream) {
    const float* x = (const float*)d_in[0];
    float* out = (float*)d_out;
    const int n = in_sizes[0] / 4;

    const size_t payload_bytes = ((size_t)n * 4u + 7u) & ~(size_t)7u;
    const size_t pfx_bytes = (size_t)B1 * NG * 2u;                 // 2,457,600
    const size_t part_bytes = (size_t)SLICES * NG * HCELLS * 8u;   // 78,643,200
    const size_t need = payload_bytes + 2u * pfx_bytes + part_bytes;

    if (ws_size < need || n > B1 * CHUNK || n <= 0) {
        hipMemsetAsync(d_out, 0, (size_t)out_size * sizeof(float), stream);
        if (n > 0)
            hipLaunchKernelGGL(e2src_hist_atomic, dim3(8192), dim3(TPB), 0, stream,
                               (const float4*)x, out, n);
        return;
    }

    uint32_t* payload = (uint32_t*)d_ws;
    uint16_t* pfx  = (uint16_t*)((char*)d_ws + payload_bytes);
    uint16_t* pfxT = (uint16_t*)((char*)d_ws + payload_bytes + pfx_bytes);
    unsigned long long* partial =
        (unsigned long long*)((char*)d_ws + payload_bytes + 2u * pfx_bytes);

    hipLaunchKernelGGL(k_bin, dim3(B1), dim3(TPB), 0, stream,
                       (const float4*)x, payload, pfx, n);
    hipLaunchKernelGGL(k_transpose, dim3((NG + 31) / 32, B1 / 32), dim3(256), 0,
                       stream, pfx, pfxT);
    hipLaunchKernelGGL(k_accum, dim3(NG * SLICES), dim3(ATPB), 0, stream,
                       payload, pfxT, partial, n);
    hipLaunchKernelGGL(k_out, dim3((NG * HCELLS) / 256), dim3(256), 0, stream,
                       partial, out);
}